// Round 7
// baseline (433.517 us; speedup 1.0000x reference)
//
#include <hip/hip_runtime.h>
#include <math.h>

#define NN 100000
#define NE 1600000
#define NG 256
#define D 128
#define EPS 1e-5f
#define MAXDEG 64
#define EPB 12800
#define SLICE_N 12500

typedef __attribute__((ext_vector_type(8))) short s16x8;
typedef __attribute__((ext_vector_type(4))) float f32x4;

__device__ __forceinline__ ushort f2b(float f) {
    uint u = __float_as_uint(f);
    uint r = (u + 0x7fffu + ((u >> 16) & 1u)) >> 16;   // RNE
    return (ushort)r;
}
__device__ __forceinline__ float blo(uint u) { return __uint_as_float(u << 16); }
__device__ __forceinline__ float bhi(uint u) { return __uint_as_float(u & 0xFFFF0000u); }

// ============ XCD-sliced slot fill ============
__global__ __launch_bounds__(256) void fill_slots_sliced(const int* __restrict__ esrc, const int* __restrict__ edst,
                                                         int* __restrict__ cursor, int* __restrict__ slots) {
    const int slice = blockIdx.x & 7;
    const int chunk = blockIdx.x >> 3;
    const int lo = slice * SLICE_N, hi = lo + SLICE_N;
    const int ebase = chunk * EPB;
    for (int i = threadIdx.x; i < EPB / 4; i += 256) {
        int e = ebase + i * 4;
        int4 s = *(const int4*)(esrc + e);
        int4 d = *(const int4*)(edst + e);
        if (d.x >= lo && d.x < hi) { int p = atomicAdd(&cursor[d.x], 1); slots[(d.x << 6) | (p & 63)] = s.x; }
        if (d.y >= lo && d.y < hi) { int p = atomicAdd(&cursor[d.y], 1); slots[(d.y << 6) | (p & 63)] = s.y; }
        if (d.z >= lo && d.z < hi) { int p = atomicAdd(&cursor[d.z], 1); slots[(d.z << 6) | (p & 63)] = s.z; }
        if (d.w >= lo && d.w < hi) { int p = atomicAdd(&cursor[d.w], 1); slots[(d.w << 6) | (p & 63)] = s.w; }
    }
}

// ============ weight transpose + cast ============
__global__ __launch_bounds__(256) void transpose_w4(const float* __restrict__ a, const float* __restrict__ b,
                                                    const float* __restrict__ c, const float* __restrict__ d,
                                                    ushort* __restrict__ Wt) {
    const float* W = (blockIdx.y == 0) ? a : (blockIdx.y == 1) ? b : (blockIdx.y == 2) ? c : d;
    ushort* T = Wt + blockIdx.y * 16384;
    for (int i = blockIdx.x * 256 + threadIdx.x; i < 16384; i += 8 * 256) {
        int k = i >> 7, cc = i & 127;
        T[(cc << 7) | k] = f2b(W[i]);
    }
}

// ============ cast x -> bf16 ============
__global__ __launch_bounds__(256) void cast_bf16(const float* __restrict__ x, ushort* __restrict__ xb, int n) {
    int i = blockIdx.x * 256 + threadIdx.x;
    if (i * 8 >= n) return;
    float4 v0 = *(const float4*)(x + i * 8);
    float4 v1 = *(const float4*)(x + i * 8 + 4);
    ushort o[8] = {f2b(v0.x), f2b(v0.y), f2b(v0.z), f2b(v0.w), f2b(v1.x), f2b(v1.y), f2b(v1.z), f2b(v1.w)};
    *(uint4*)(xb + i * 8) = *(uint4*)o;
}

// ============ gather, 8 rows in flight, optional fused BN+ReLU ============
template <int FUSE_BN>
__global__ __launch_bounds__(256) void gather_slots(ushort* __restrict__ out, const ushort* __restrict__ feat,
                                                    const int* __restrict__ deg, const int* __restrict__ slots,
                                                    const float* __restrict__ scale, const float* __restrict__ shift) {
    int node = __builtin_amdgcn_readfirstlane(blockIdx.x * 4 + (threadIdx.x >> 6));
    if (node >= NN) return;
    int lane = threadIdx.x & 63;
    int n = deg[node];
    n = (n > MAXDEG) ? MAXDEG : n;
    const int* sl = slots + (node << 6);
    float scx = 1.f, scy = 1.f, shx = 0.f, shy = 0.f;
    if (FUSE_BN) {
        float2 sc = *(const float2*)(scale + lane * 2);
        float2 sh = *(const float2*)(shift + lane * 2);
        scx = sc.x; scy = sc.y; shx = sh.x; shy = sh.y;
    }
    uint ub = *(const uint*)(feat + node * D + lane * 2);
    float axv[8], ayv[8];
#pragma unroll
    for (int j = 0; j < 8; ++j) { axv[j] = 0.f; ayv[j] = 0.f; }
    if (FUSE_BN) {
        axv[0] = fmaxf(fmaf(blo(ub), scx, shx), 0.f);
        ayv[0] = fmaxf(fmaf(bhi(ub), scy, shy), 0.f);
    } else {
        axv[0] = blo(ub); ayv[0] = bhi(ub);
    }
    int e = 0;
    for (; e + 7 < n; e += 8) {
        uint u[8];
#pragma unroll
        for (int j = 0; j < 8; ++j) u[j] = *(const uint*)(feat + sl[e + j] * D + lane * 2);
#pragma unroll
        for (int j = 0; j < 8; ++j) {
            if (FUSE_BN) {
                axv[j] += fmaxf(fmaf(blo(u[j]), scx, shx), 0.f);
                ayv[j] += fmaxf(fmaf(bhi(u[j]), scy, shy), 0.f);
            } else {
                axv[j] += blo(u[j]); ayv[j] += bhi(u[j]);
            }
        }
    }
    for (; e < n; ++e) {
        uint u0 = *(const uint*)(feat + sl[e] * D + lane * 2);
        if (FUSE_BN) {
            axv[0] += fmaxf(fmaf(blo(u0), scx, shx), 0.f);
            ayv[0] += fmaxf(fmaf(bhi(u0), scy, shy), 0.f);
        } else {
            axv[0] += blo(u0); ayv[0] += bhi(u0);
        }
    }
    float ax = ((axv[0] + axv[1]) + (axv[2] + axv[3])) + ((axv[4] + axv[5]) + (axv[6] + axv[7]));
    float ay = ((ayv[0] + ayv[1]) + (ayv[2] + ayv[3])) + ((ayv[4] + ayv[5]) + (ayv[6] + ayv[7]));
    uint o = (uint)f2b(ax) | ((uint)f2b(ay) << 16);
    *(uint*)(out + node * D + lane * 2) = o;
}

// ============ fused dual GEMM + BN stats ============
// H = (relu(G@Wa+ba)) @ Wb + bb ; also sum/sumsq columns of (bf16-rounded) H.
// block: 256 thr = 4 waves, 128 rows x 128 cols. T kept in swizzled LDS.
__global__ __launch_bounds__(256) void gemm_dual(const ushort* __restrict__ G,
                                                 const ushort* __restrict__ Wta, const float* __restrict__ ba,
                                                 const ushort* __restrict__ Wtb, const float* __restrict__ bb,
                                                 ushort* __restrict__ H, double* __restrict__ sum,
                                                 double* __restrict__ sumsq, int nrows) {
    __shared__ ushort tile[16384];      // 128 x 128 bf16, 16B-slot XOR swizzle
    __shared__ float4 red[4][64];
    char* tb = (char*)tile;

    const int tid = threadIdx.x;
    const int lane = tid & 63;
    const int wave = tid >> 6;
    const int r0g = blockIdx.x * 128 + wave * 32;   // global row base of wave
    const int r0l = wave * 32;                      // local row base in tile
    const int lr = lane & 15;
    const int kg = lane >> 4;
    const int cb = kg * 4;

    // ---- stage 1: acc1 = G @ Wa ----
    f32x4 acc[2][8];
#pragma unroll
    for (int rt = 0; rt < 2; ++rt)
#pragma unroll
        for (int ct = 0; ct < 8; ++ct) acc[rt][ct] = (f32x4)0.f;

    {
        int row0 = r0g + lr;       if (row0 > nrows - 1) row0 = nrows - 1;
        int row1 = r0g + 16 + lr;  if (row1 > nrows - 1) row1 = nrows - 1;
        const ushort* a0p = G + row0 * D + kg * 8;
        const ushort* a1p = G + row1 * D + kg * 8;
        const ushort* wp = Wta + lr * D + kg * 8;
#pragma unroll
        for (int ks = 0; ks < 4; ++ks) {
            s16x8 b0 = *(const s16x8*)(a0p + ks * 32);
            s16x8 b1 = *(const s16x8*)(a1p + ks * 32);
#pragma unroll
            for (int ct = 0; ct < 8; ++ct) {
                s16x8 a = *(const s16x8*)(wp + ct * 2048 + ks * 32);
                acc[0][ct] = __builtin_amdgcn_mfma_f32_16x16x32_bf16(a, b0, acc[0][ct], 0, 0, 0);
                acc[1][ct] = __builtin_amdgcn_mfma_f32_16x16x32_bf16(a, b1, acc[1][ct], 0, 0, 0);
            }
        }
    }

    // ---- T = relu(acc1 + ba) -> LDS (swizzled) ----
#pragma unroll
    for (int ct = 0; ct < 8; ++ct) {
        float4 bv = *(const float4*)(ba + ct * 16 + cb);
#pragma unroll
        for (int rt = 0; rt < 2; ++rt) {
            int row = r0l + rt * 16 + lr;
            float o0 = fmaxf(acc[rt][ct][0] + bv.x, 0.f);
            float o1 = fmaxf(acc[rt][ct][1] + bv.y, 0.f);
            float o2 = fmaxf(acc[rt][ct][2] + bv.z, 0.f);
            float o3 = fmaxf(acc[rt][ct][3] + bv.w, 0.f);
            ushort pk[4] = {f2b(o0), f2b(o1), f2b(o2), f2b(o3)};
            int off = row * 256 + ((ct * 32 + kg * 8) ^ ((row & 7) << 4));
            *(uint2*)(tb + off) = *(const uint2*)pk;
        }
    }
    __syncthreads();

    // ---- stage 2: acc2 = T @ Wb ----
#pragma unroll
    for (int rt = 0; rt < 2; ++rt)
#pragma unroll
        for (int ct = 0; ct < 8; ++ct) acc[rt][ct] = (f32x4)0.f;
    {
        const ushort* wp = Wtb + lr * D + kg * 8;
        int rowA = r0l + lr, rowB = r0l + 16 + lr;
#pragma unroll
        for (int ks = 0; ks < 4; ++ks) {
            s16x8 b0 = *(const s16x8*)(tb + rowA * 256 + ((ks * 64 + kg * 16) ^ ((rowA & 7) << 4)));
            s16x8 b1 = *(const s16x8*)(tb + rowB * 256 + ((ks * 64 + kg * 16) ^ ((rowB & 7) << 4)));
#pragma unroll
            for (int ct = 0; ct < 8; ++ct) {
                s16x8 a = *(const s16x8*)(wp + ct * 2048 + ks * 32);
                acc[0][ct] = __builtin_amdgcn_mfma_f32_16x16x32_bf16(a, b0, acc[0][ct], 0, 0, 0);
                acc[1][ct] = __builtin_amdgcn_mfma_f32_16x16x32_bf16(a, b1, acc[1][ct], 0, 0, 0);
            }
        }
    }
    __syncthreads();   // all T reads complete before tile is overwritten with H

    // ---- H = acc2 + bb: write to global + LDS (zeros for invalid rows) ----
#pragma unroll
    for (int ct = 0; ct < 8; ++ct) {
        float4 bv = *(const float4*)(bb + ct * 16 + cb);
#pragma unroll
        for (int rt = 0; rt < 2; ++rt) {
            int rowl = r0l + rt * 16 + lr;
            int rowg = r0g + rt * 16 + lr;
            uint2 pk2 = make_uint2(0u, 0u);
            if (rowg < nrows) {
                float o0 = acc[rt][ct][0] + bv.x;
                float o1 = acc[rt][ct][1] + bv.y;
                float o2 = acc[rt][ct][2] + bv.z;
                float o3 = acc[rt][ct][3] + bv.w;
                ushort pk[4] = {f2b(o0), f2b(o1), f2b(o2), f2b(o3)};
                pk2 = *(const uint2*)pk;
                *(uint2*)(H + rowg * D + ct * 16 + cb) = pk2;
            }
            int off = rowl * 256 + ((ct * 32 + kg * 8) ^ ((rowl & 7) << 4));
            *(uint2*)(tb + off) = pk2;
        }
    }
    __syncthreads();

    // ---- column stats: rg = tid>>6 covers 32 rows; cpair = tid&63 covers 2 cols ----
    {
        int rg = tid >> 6, cpair = tid & 63;
        float s0 = 0.f, q0 = 0.f, s1 = 0.f, q1 = 0.f;
#pragma unroll 8
        for (int i = 0; i < 32; ++i) {
            int row = rg * 32 + i;
            uint u = *(const uint*)(tb + row * 256 + ((cpair * 4) ^ ((row & 7) << 4)));
            float lo = blo(u), hi = bhi(u);
            s0 += lo; q0 += lo * lo; s1 += hi; q1 += hi * hi;
        }
        red[rg][cpair] = make_float4(s0, q0, s1, q1);
    }
    __syncthreads();
    if (tid < 64) {
        float4 a = red[0][tid];
        float4 b = red[1][tid];
        float4 c = red[2][tid];
        float4 d = red[3][tid];
        float sx = (a.x + b.x) + (c.x + d.x);
        float qx = (a.y + b.y) + (c.y + d.y);
        float sy = (a.z + b.z) + (c.z + d.z);
        float qy = (a.w + b.w) + (c.w + d.w);
        atomicAdd(&sum[2 * tid], (double)sx);
        atomicAdd(&sumsq[2 * tid], (double)qx);
        atomicAdd(&sum[2 * tid + 1], (double)sy);
        atomicAdd(&sumsq[2 * tid + 1], (double)qy);
    }
}

__global__ __launch_bounds__(128) void bn_finalize(const double* __restrict__ sum, const double* __restrict__ sumsq,
                                                   const float* __restrict__ gamma, const float* __restrict__ beta,
                                                   float* __restrict__ scale, float* __restrict__ shift, int nrows) {
    int f = threadIdx.x;
    double mean = sum[f] / nrows;
    double var = sumsq[f] / nrows - mean * mean;
    float sc = gamma[f] * rsqrtf((float)var + EPS);
    scale[f] = sc;
    shift[f] = beta[f] - (float)mean * sc;
}

// ============ pool: partial sums into pooled[g][f] via run-flush atomics ============
__global__ __launch_bounds__(256) void pool_partial(const ushort* __restrict__ h, const int* __restrict__ batch,
                                                    const float* __restrict__ scale, const float* __restrict__ shift,
                                                    float* __restrict__ pooled) {
    int wave = threadIdx.x >> 6;
    int lane = threadIdx.x & 63;
    int r0 = blockIdx.x * 256 + wave * 64;
    if (r0 >= NN) return;
    int f2 = lane * 2;
    float2 sc = *(const float2*)(scale + f2);
    float2 sh = *(const float2*)(shift + f2);
    float ax = 0.f, ay = 0.f;
    int cur = -1;
    int rend = r0 + 64; if (rend > NN) rend = NN;
    for (int r = r0; r < rend; ++r) {
        int g = batch[r];
        if (g != cur) {
            if (cur >= 0) {
                atomicAdd(&pooled[cur * D + f2], ax);
                atomicAdd(&pooled[cur * D + f2 + 1], ay);
            }
            cur = g; ax = 0.f; ay = 0.f;
        }
        uint u = *(const uint*)(h + r * D + f2);
        ax += fmaxf(fmaf(blo(u), sc.x, sh.x), 0.f);
        ay += fmaxf(fmaf(bhi(u), sc.y, sh.y), 0.f);
    }
    if (cur >= 0) {
        atomicAdd(&pooled[cur * D + f2], ax);
        atomicAdd(&pooled[cur * D + f2 + 1], ay);
    }
}

__device__ __forceinline__ int lower_bound_i(const int* a, int n, int v) {
    int lo = 0, hi = n;
    while (lo < hi) {
        int m = (lo + hi) >> 1;
        if (a[m] < v) lo = m + 1; else hi = m;
    }
    return lo;
}

__global__ __launch_bounds__(256) void head(const float* __restrict__ pooled, const int* __restrict__ batch,
                                            const float* __restrict__ wl, const float* __restrict__ bl,
                                            float* __restrict__ out) {
    int g = blockIdx.x * 256 + threadIdx.x;
    if (g >= NG) return;
    int lo = lower_bound_i(batch, NN, g);
    int hi = lower_bound_i(batch, NN, g + 1);
    float inv = 1.f / fmaxf((float)(hi - lo), 1.f);
    float logits[7];
#pragma unroll
    for (int c = 0; c < 7; ++c) logits[c] = bl[c];
    for (int k = 0; k < D; ++k) {
        float p = pooled[g * D + k] * inv;
#pragma unroll
        for (int c = 0; c < 7; ++c) logits[c] = fmaf(p, wl[k * 7 + c], logits[c]);
    }
    float m = logits[0];
#pragma unroll
    for (int c = 1; c < 7; ++c) m = fmaxf(m, logits[c]);
    float s = 0.f;
#pragma unroll
    for (int c = 0; c < 7; ++c) s += expf(logits[c] - m);
    float lse = m + logf(s);
#pragma unroll
    for (int c = 0; c < 7; ++c) out[g * 7 + c] = logits[c] - lse;
}

extern "C" void kernel_launch(void* const* d_in, const int* in_sizes, int n_in,
                              void* d_out, int out_size, void* d_ws, size_t ws_size,
                              hipStream_t stream) {
    const float* x   = (const float*)d_in[0];
    const float* w1a = (const float*)d_in[1];
    const float* b1a = (const float*)d_in[2];
    const float* w1b = (const float*)d_in[3];
    const float* b1b = (const float*)d_in[4];
    const float* g1  = (const float*)d_in[5];
    const float* be1 = (const float*)d_in[6];
    const float* w2a = (const float*)d_in[7];
    const float* b2a = (const float*)d_in[8];
    const float* w2b = (const float*)d_in[9];
    const float* b2b = (const float*)d_in[10];
    const float* g2  = (const float*)d_in[11];
    const float* be2 = (const float*)d_in[12];
    const float* wl  = (const float*)d_in[13];
    const float* bl  = (const float*)d_in[14];
    const int* ei    = (const int*)d_in[15];
    const int* batch = (const int*)d_in[16];
    float* out = (float*)d_out;

    const int* esrc = ei;
    const int* edst = ei + NE;

    char* ws = (char*)d_ws;
    ushort* B0 = (ushort*)(ws);                   // xb ; later G2
    ushort* B1 = (ushort*)(ws + 25600000);        // G1 ; later H2
    ushort* B2 = (ushort*)(ws + 51200000);        // H1
    int* slots   = (int*)(ws + 76800000);         // NN*64 ints
    int* cursor  = (int*)(ws + 102400000);        // NN ints (degree)
    double* sum1 = (double*)(ws + 102800000);
    double* sq1  = sum1 + 128;
    double* sum2 = sq1 + 128;
    double* sq2  = sum2 + 128;
    float* scale1 = (float*)(ws + 102804096);
    float* shift1 = scale1 + 128;
    float* scale2 = shift1 + 128;
    float* shift2 = scale2 + 128;
    float* pooled = (float*)(ws + 102806144);     // 256*128 f
    ushort* Wt    = (ushort*)(ws + 102937216);
    ushort* Wt1a = Wt, *Wt1b = Wt + 16384, *Wt2a = Wt + 32768, *Wt2b = Wt + 49152;

    const int grid_fill = (NE / EPB) * 8;             // 1000
    const int grid_gemm = (NN + 127) / 128;           // 782
    const int grid_stat = (NN + 255) / 256;           // 391
    const int grid_gath = (NN + 3) / 4;               // 25000
    const int grid_cast = (NN * D / 8 + 255) / 256;   // 6250

    // memset covers cursor + BN sums + scales + pooled: [102400000, 102937216)
    hipMemsetAsync(cursor, 0, 537216, stream);

    fill_slots_sliced<<<grid_fill, 256, 0, stream>>>(esrc, edst, cursor, slots);
    transpose_w4<<<dim3(8, 4), 256, 0, stream>>>(w1a, w1b, w2a, w2b, Wt);
    cast_bf16<<<grid_cast, 256, 0, stream>>>(x, B0, NN * D);

    // ---- layer 1 ----
    gather_slots<0><<<grid_gath, 256, 0, stream>>>(B1, B0, cursor, slots, nullptr, nullptr);   // B1 = x+agg
    gemm_dual<<<grid_gemm, 256, 0, stream>>>(B1, Wt1a, b1a, Wt1b, b1b, B2, sum1, sq1, NN);     // B2 = h1
    bn_finalize<<<1, 128, 0, stream>>>(sum1, sq1, g1, be1, scale1, shift1, NN);

    // ---- layer 2 (BN1+ReLU fused into gather) ----
    gather_slots<1><<<grid_gath, 256, 0, stream>>>(B0, B2, cursor, slots, scale1, shift1);     // B0 = h1n+agg
    gemm_dual<<<grid_gemm, 256, 0, stream>>>(B0, Wt2a, b2a, Wt2b, b2b, B1, sum2, sq2, NN);     // B1 = h2
    bn_finalize<<<1, 128, 0, stream>>>(sum2, sq2, g2, be2, scale2, shift2, NN);

    // ---- pool + head ----
    pool_partial<<<grid_stat, 256, 0, stream>>>(B1, batch, scale2, shift2, pooled);
    head<<<1, 256, 0, stream>>>(pooled, batch, wl, bl, out);
}